// Round 13
// baseline (198.315 us; speedup 1.0000x reference)
//
#include <hip/hip_runtime.h>

#define S_LEN 2048
#define BATCH_N 2
#define DM 512
#define H_N 8
#define DK_N 64
#define FF_N 2048
#define M_TOK (S_LEN*BATCH_N)  // 4096
#define QSZ (BATCH_N*H_N*S_LEN*DK_N)  // 2097152 elements per q/k/v plane
#define MN_PART 2097152          // 4096*512 elems per FFN2 partial (bf16)

typedef __attribute__((ext_vector_type(8))) short short8;
typedef __attribute__((ext_vector_type(4))) float f32x4;
typedef __attribute__((ext_vector_type(16))) float f32x16;
typedef __attribute__((ext_vector_type(4))) unsigned uint4v;

__device__ __forceinline__ unsigned short f2b(float f) {
  union { float f; unsigned u; } v; v.f = f;
  unsigned r = v.u + 0x7FFFu + ((v.u >> 16) & 1u);
  return (unsigned short)(r >> 16);
}
__device__ __forceinline__ float b2f(unsigned short u) {
  union { unsigned u; float f; } v; v.u = ((unsigned)u) << 16; return v.f;
}

// async global->LDS, 16B per lane (dest = wave-uniform base + lane*16).
__device__ __forceinline__ void gl_lds16(const void* g, void* l) {
  __builtin_amdgcn_global_load_lds(
      (__attribute__((address_space(1))) unsigned int*)(unsigned long long)g,
      (__attribute__((address_space(3))) unsigned int*)(unsigned int)(unsigned long long)l,
      16, 0, 0);
}

__device__ __forceinline__ void cast4(const float* __restrict__ src,
                                      unsigned short* __restrict__ dst, int i) {
  float4 v = *(const float4*)(src + i);
  ushort4 o; o.x = f2b(v.x); o.y = f2b(v.y); o.z = f2b(v.z); o.w = f2b(v.w);
  *(ushort4*)(dst + i) = o;
}

// ---- wave-per-row LayerNorm (512 cols, 8 f32/lane, shfl-only) ----
__device__ __forceinline__ void ln_row_wave(const float* __restrict__ in,
    const float* __restrict__ g, const float* __restrict__ b,
    unsigned short* __restrict__ out, int row, int lane) {
  const float4* src = (const float4*)(in + (size_t)row * DM);
  float4 v0 = src[lane*2], v1 = src[lane*2 + 1];
  float s  = v0.x+v0.y+v0.z+v0.w + v1.x+v1.y+v1.z+v1.w;
  float ss = v0.x*v0.x+v0.y*v0.y+v0.z*v0.z+v0.w*v0.w
           + v1.x*v1.x+v1.y*v1.y+v1.z*v1.z+v1.w*v1.w;
  #pragma unroll
  for (int off = 32; off >= 1; off >>= 1) {
    s  += __shfl_xor(s,  off);
    ss += __shfl_xor(ss, off);
  }
  float mean = s * (1.f/512.f);
  float inv  = rsqrtf(ss * (1.f/512.f) - mean*mean + 1e-5f);
  float4 g0 = ((const float4*)g)[lane*2], g1 = ((const float4*)g)[lane*2 + 1];
  float4 b0 = ((const float4*)b)[lane*2], b1 = ((const float4*)b)[lane*2 + 1];
  ushort4 o0, o1;
  o0.x = f2b((v0.x-mean)*inv*g0.x + b0.x);
  o0.y = f2b((v0.y-mean)*inv*g0.y + b0.y);
  o0.z = f2b((v0.z-mean)*inv*g0.z + b0.z);
  o0.w = f2b((v0.w-mean)*inv*g0.w + b0.w);
  o1.x = f2b((v1.x-mean)*inv*g1.x + b1.x);
  o1.y = f2b((v1.y-mean)*inv*g1.y + b1.y);
  o1.z = f2b((v1.z-mean)*inv*g1.z + b1.z);
  o1.w = f2b((v1.w-mean)*inv*g1.w + b1.w);
  ushort4* dst = (ushort4*)(out + (size_t)row * DM);
  dst[lane*2]     = o0;
  dst[lane*2 + 1] = o1;
}

// ---- fused prep: weight/memory casts + mask pack + LN1 ----
__global__ __launch_bounds__(256) void prep_kernel(
    const float* __restrict__ sa_W, const float* __restrict__ ca_W,
    const float* __restrict__ w1, const float* __restrict__ w2,
    const float* __restrict__ memory, const int* __restrict__ mm,
    const float* __restrict__ x, const float* __restrict__ ln_g,
    const float* __restrict__ ln_b,
    unsigned short* __restrict__ o_sa, unsigned short* __restrict__ o_ca,
    unsigned short* __restrict__ o_w1, unsigned short* __restrict__ o_w2,
    unsigned short* __restrict__ o_mem, unsigned long long* __restrict__ bmo,
    unsigned short* __restrict__ nx)
{
  int blk = blockIdx.x, t = threadIdx.x;
  if (blk < 1024)      cast4(sa_W, o_sa, (blk*256 + t)*4);
  else if (blk < 2048) cast4(ca_W, o_ca, ((blk-1024)*256 + t)*4);
  else if (blk < 3072) cast4(w1,   o_w1, ((blk-2048)*256 + t)*4);
  else if (blk < 4096) cast4(w2,   o_w2, ((blk-3072)*256 + t)*4);
  else if (blk < 6144) cast4(memory, o_mem, ((blk-4096)*256 + t)*4);
  else if (blk == 6144) {
    if (t < 64) {
      int b = t >> 5, kt = t & 31;
      unsigned long long m = 0ull;
      for (int j = 0; j < 64; j++)
        m |= (unsigned long long)(mm[b*S_LEN + kt*64 + j] != 0) << j;
      bmo[b*32 + kt] = m;
    }
  } else {
    int row = (blk - 6145)*4 + (t >> 6);
    ln_row_wave(x, ln_g, ln_b, nx, row, t & 63);
  }
}

// ---- standalone LN (4 rows / 256-thr block) ----
__global__ __launch_bounds__(256) void ln4_kernel(const float* __restrict__ in,
                                                  const float* __restrict__ g,
                                                  const float* __restrict__ b,
                                                  unsigned short* __restrict__ out) {
  ln_row_wave(in, g, b, out, blockIdx.x*4 + (threadIdx.x >> 6), threadIdx.x & 63);
}

// ---- 64x64-tile GEMM, dbuf single-barrier.
// OUTMODE 0: f32 +resid, 1: bf16, 2: bf16 qkv scatter (Q plane pre-scaled 1/8),
// 3: bf16 split-K partial (no bias).
template<int RELU, int OUTMODE, int RESID>
__global__ __launch_bounds__(256) void gemm_bt(
    const unsigned short* __restrict__ A, const unsigned short* __restrict__ W,
    const float* __restrict__ bias, const float* __restrict__ resid,
    float* __restrict__ Cf, unsigned short* __restrict__ Cb,
    int M, int N, int K, int Kstride)
{
  __shared__ unsigned short As[2][64*40];
  __shared__ unsigned short Bs[2][64*40];
  int tid = threadIdx.x;
  int lane = tid & 63, w = tid >> 6;
  int wr = w >> 1, wc = w & 1;
  int bm = blockIdx.y * 64, bn = blockIdx.x * 64;
  int kz = blockIdx.z;
  f32x4 acc[2][2] = {};
  int lrow = tid >> 2;
  int lcg  = (tid & 3) * 8;
  const size_t aoff = (size_t)(bm + lrow) * Kstride + (size_t)kz * K + lcg;
  const size_t boff = (size_t)(bn + lrow) * Kstride + (size_t)kz * K + lcg;
  int fr = lane & 15, kg = (lane >> 4) * 8;
  short8 pa = *(const short8*)&A[aoff];
  short8 pb = *(const short8*)&W[boff];
  *(short8*)&As[0][lrow*40 + lcg] = pa;
  *(short8*)&Bs[0][lrow*40 + lcg] = pb;
  __syncthreads();
  int cur = 0;
  for (int k0 = 0; k0 < K; k0 += 32) {
    bool hn = (k0 + 32) < K;
    if (hn) {
      pa = *(const short8*)&A[aoff + k0 + 32];
      pb = *(const short8*)&W[boff + k0 + 32];
    }
    short8 af0 = *(const short8*)&As[cur][(wr*32 +      fr)*40 + kg];
    short8 af1 = *(const short8*)&As[cur][(wr*32 + 16 + fr)*40 + kg];
    short8 bf0 = *(const short8*)&Bs[cur][(wc*32 +      fr)*40 + kg];
    short8 bf1 = *(const short8*)&Bs[cur][(wc*32 + 16 + fr)*40 + kg];
    acc[0][0] = __builtin_amdgcn_mfma_f32_16x16x32_bf16(af0, bf0, acc[0][0], 0,0,0);
    acc[0][1] = __builtin_amdgcn_mfma_f32_16x16x32_bf16(af0, bf1, acc[0][1], 0,0,0);
    acc[1][0] = __builtin_amdgcn_mfma_f32_16x16x32_bf16(af1, bf0, acc[1][0], 0,0,0);
    acc[1][1] = __builtin_amdgcn_mfma_f32_16x16x32_bf16(af1, bf1, acc[1][1], 0,0,0);
    if (hn) {
      *(short8*)&As[cur^1][lrow*40 + lcg] = pa;
      *(short8*)&Bs[cur^1][lrow*40 + lcg] = pb;
    }
    __syncthreads();
    cur ^= 1;
  }
  int rbase = (lane >> 4) * 4;
  #pragma unroll
  for (int m = 0; m < 2; m++) {
    #pragma unroll
    for (int n = 0; n < 2; n++) {
      int col = bn + wc*32 + n*16 + (lane & 15);
      float bc = (OUTMODE == 3) ? 0.f : bias[col];
      #pragma unroll
      for (int r = 0; r < 4; r++) {
        int row = bm + wr*32 + m*16 + rbase + r;
        float vv = acc[m][n][r] + bc;
        if (RELU) vv = fmaxf(vv, 0.f);
        if (OUTMODE == 2) {
          int which = col >> 9, hh = (col >> 6) & 7, dd = col & 63;
          if (which == 0) vv *= 0.125f;   // fold 1/sqrt(dk) into Q plane
          size_t idx = ((((size_t)which*BATCH_N + (row & 1))*H_N + hh)*S_LEN + (row >> 1))*DK_N + dd;
          Cb[idx] = f2b(vv);
        } else if (OUTMODE == 3) {
          Cb[(size_t)kz*MN_PART + (size_t)row*N + col] = f2b(vv);
        } else {
          size_t idx = (size_t)row * N + col;
          if (RESID) vv += resid[idx];
          if (OUTMODE == 1) Cb[idx] = f2b(vv);
          else              Cf[idx] = vv;
        }
      }
    }
  }
}

// ---- FFN2 split-K(2) combine: out = p0 + p1 + bias + resid (partials bf16) ----
__global__ __launch_bounds__(256) void ffn2_combine(
    const unsigned short* __restrict__ part, const float* __restrict__ bias,
    const float* __restrict__ resid, float* __restrict__ out)
{
  int i = (blockIdx.x*256 + threadIdx.x)*8;
  short8 a = *(const short8*)&part[i];
  short8 b = *(const short8*)&part[MN_PART + i];
  float4 bs0 = *(const float4*)(bias + (i & 511));
  float4 bs1 = *(const float4*)(bias + ((i & 511) + 4));
  float4 rs0 = *(const float4*)(resid + i);
  float4 rs1 = *(const float4*)(resid + i + 4);
  float4 o0, o1;
  o0.x = b2f((unsigned short)a[0]) + b2f((unsigned short)b[0]) + bs0.x + rs0.x;
  o0.y = b2f((unsigned short)a[1]) + b2f((unsigned short)b[1]) + bs0.y + rs0.y;
  o0.z = b2f((unsigned short)a[2]) + b2f((unsigned short)b[2]) + bs0.z + rs0.z;
  o0.w = b2f((unsigned short)a[3]) + b2f((unsigned short)b[3]) + bs0.w + rs0.w;
  o1.x = b2f((unsigned short)a[4]) + b2f((unsigned short)b[4]) + bs1.x + rs1.x;
  o1.y = b2f((unsigned short)a[5]) + b2f((unsigned short)b[5]) + bs1.y + rs1.y;
  o1.z = b2f((unsigned short)a[6]) + b2f((unsigned short)b[6]) + bs1.z + rs1.z;
  o1.w = b2f((unsigned short)a[7]) + b2f((unsigned short)b[7]) + bs1.w + rs1.w;
  *(float4*)(out + i)     = o0;
  *(float4*)(out + i + 4) = o1;
}

// ---- 128x128-tile GEMM, global_load_lds staging (FFN1) ----
template<int RELU, int OUTMODE, int VSTART>
__global__ __launch_bounds__(256) void gemm128(
    const unsigned short* __restrict__ A, const unsigned short* __restrict__ W,
    const float* __restrict__ bias, unsigned short* __restrict__ Cb,
    int M, int N, int K)
{
  __shared__ unsigned short As[128*32];
  __shared__ unsigned short Bs[128*32];
  int tid = threadIdx.x, lane = tid & 63, w = tid >> 6;
  int bm = blockIdx.y * 128, bn = blockIdx.x * 128;
  int fr = lane & 15, hi = lane >> 4;
  int kg8 = hi*8, rg = hi*4;
  int wm = (w >> 1) * 64, wn = (w & 1) * 64;
  f32x4 acc[4][4] = {};
  const unsigned short* ga0 = A + (size_t)(bm +      (tid>>2))*K + (tid&3)*8;
  const unsigned short* ga1 = A + (size_t)(bm + 64 + (tid>>2))*K + (tid&3)*8;
  const unsigned short* gb0 = W + (size_t)(bn +      (tid>>2))*K + (tid&3)*8;
  const unsigned short* gb1 = W + (size_t)(bn + 64 + (tid>>2))*K + (tid&3)*8;
  unsigned short* lA0 = &As[tid*8];
  unsigned short* lA1 = &As[2048 + tid*8];
  unsigned short* lB0 = &Bs[tid*8];
  unsigned short* lB1 = &Bs[2048 + tid*8];
  for (int k0 = 0; k0 < K; k0 += 32) {
    gl_lds16(ga0 + k0, lA0);
    gl_lds16(ga1 + k0, lA1);
    gl_lds16(gb0 + k0, lB0);
    gl_lds16(gb1 + k0, lB1);
    __syncthreads();
    short8 af[4], bf[4];
    #pragma unroll
    for (int m = 0; m < 4; m++) af[m] = *(const short8*)&As[(wm + m*16 + fr)*32 + kg8];
    #pragma unroll
    for (int n = 0; n < 4; n++) bf[n] = *(const short8*)&Bs[(wn + n*16 + fr)*32 + kg8];
    __builtin_amdgcn_s_setprio(1);
    #pragma unroll
    for (int m = 0; m < 4; m++)
      #pragma unroll
      for (int n = 0; n < 4; n++)
        acc[m][n] = __builtin_amdgcn_mfma_f32_16x16x32_bf16(af[m], bf[n], acc[m][n], 0,0,0);
    __builtin_amdgcn_s_setprio(0);
    __syncthreads();
  }
  #pragma unroll
  for (int m = 0; m < 4; m++) {
    #pragma unroll
    for (int n = 0; n < 4; n++) {
      int col = bn + wn + n*16 + fr;
      float bc = bias[col];
      #pragma unroll
      for (int r = 0; r < 4; r++) {
        int row = bm + wm + m*16 + rg + r;
        float vv = acc[m][n][r] + bc;
        if (RELU) vv = fmaxf(vv, 0.f);
        if (OUTMODE == 2) {
          int which = col >> 9, hh = (col >> 6) & 7, dd = col & 63;
          int srow = row >> 1, bb = row & 1;
          size_t idx;
          if (which >= VSTART)
            idx = (size_t)which*QSZ + (((size_t)bb*H_N + hh)*DK_N + dd)*S_LEN + srow;
          else
            idx = (size_t)which*QSZ + (((size_t)bb*H_N + hh)*S_LEN + srow)*DK_N + dd;
          Cb[idx] = f2b(vv);
        } else {
          Cb[(size_t)row * N + col] = f2b(vv);
        }
      }
    }
  }
}

// ---- merged self-QKV (12 col-tiles) + cross-KV (8 col-tiles) GEMM ----
// Self Q plane (vs==2, which==0) is pre-scaled by 1/8 (1/sqrt(dk)).
__global__ __launch_bounds__(256) void gemm128_dual(
    const unsigned short* __restrict__ A0, const unsigned short* __restrict__ W0,
    const float* __restrict__ bias0, unsigned short* __restrict__ C0,
    const unsigned short* __restrict__ A1, const unsigned short* __restrict__ W1,
    const float* __restrict__ bias1, unsigned short* __restrict__ C1)
{
  const int K = 512;
  int bx = blockIdx.x;
  const unsigned short* A; const unsigned short* W; const float* bias;
  unsigned short* Cb; int bn, vs;
  if (bx < 12) { A = A0; W = W0; bias = bias0; Cb = C0; bn = bx*128;      vs = 2; }
  else         { A = A1; W = W1; bias = bias1; Cb = C1; bn = (bx-12)*128; vs = 1; }
  __shared__ unsigned short As[128*32];
  __shared__ unsigned short Bs[128*32];
  int tid = threadIdx.x, lane = tid & 63, w = tid >> 6;
  int bm = blockIdx.y * 128;
  int fr = lane & 15, hi = lane >> 4;
  int kg8 = hi*8, rg = hi*4;
  int wm = (w >> 1) * 64, wn = (w & 1) * 64;
  f32x4 acc[4][4] = {};
  const unsigned short* ga0 = A + (size_t)(bm +      (tid>>2))*K + (tid&3)*8;
  const unsigned short* ga1 = A + (size_t)(bm + 64 + (tid>>2))*K + (tid&3)*8;
  const unsigned short* gb0 = W + (size_t)(bn +      (tid>>2))*K + (tid&3)*8;
  const unsigned short* gb1 = W + (size_t)(bn + 64 + (tid>>2))*K + (tid&3)*8;
  unsigned short* lA0 = &As[tid*8];
  unsigned short* lA1 = &As[2048 + tid*8];
  unsigned short* lB0 = &Bs[tid*8];
  unsigned short* lB1 = &Bs[2048 + tid*8];
  for (int k0 = 0; k0 < K; k0 += 32) {
    gl_lds16(ga0 + k0, lA0);
    gl_lds16(ga1 + k0, lA1);
    gl_lds16(gb0 + k0, lB0);
    gl_lds16(gb1 + k0, lB1);
    __syncthreads();
    short8 af[4], bf[4];
    #pragma unroll
    for (int m = 0; m < 4; m++) af[m] = *(const short8*)&As[(wm + m*16 + fr)*32 + kg8];
    #pragma unroll
    for (int n = 0; n < 4; n++) bf[n] = *(const short8*)&Bs[(wn + n*16 + fr)*32 + kg8];
    __builtin_amdgcn_s_setprio(1);
    #pragma unroll
    for (int m = 0; m < 4; m++)
      #pragma unroll
      for (int n = 0; n < 4; n++)
        acc[m][n] = __builtin_amdgcn_mfma_f32_16x16x32_bf16(af[m], bf[n], acc[m][n], 0,0,0);
    __builtin_amdgcn_s_setprio(0);
    __syncthreads();
  }
  #pragma unroll
  for (int m = 0; m < 4; m++) {
    #pragma unroll
    for (int n = 0; n < 4; n++) {
      int col = bn + wn + n*16 + fr;
      float bc = bias[col];
      #pragma unroll
      for (int r = 0; r < 4; r++) {
        int row = bm + wm + m*16 + rg + r;
        float vv = acc[m][n][r] + bc;
        int which = col >> 9, hh = (col >> 6) & 7, dd = col & 63;
        if (vs == 2 && which == 0) vv *= 0.125f;   // Q plane pre-scale
        int srow = row >> 1, bb = row & 1;
        size_t idx;
        if (which >= vs)
          idx = (size_t)which*QSZ + (((size_t)bb*H_N + hh)*DK_N + dd)*S_LEN + srow;
        else
          idx = (size_t)which*QSZ + (((size_t)bb*H_N + hh)*S_LEN + srow)*DK_N + dd;
        Cb[idx] = f2b(vv);
      }
    }
  }
}

// ---- 32x32-MFMA flash attention, KVBLK=128: 128 q-rows/block, wave owns rows ----
// Q pre-scaled by 1/sqrt(dk). 128-key tiles (4x fewer barriers per range than 64-key
// at same occupancy: LDS 35.8 KB x 4 blocks/CU = 143 KB). Per-kb wave-uniform
// causal skip/mask. Inactive causal blocks return WITHOUT writing.
// lpart layout: [pr][4].
template<int MODE>
__global__ __launch_bounds__(256, 4) void attn4(
    const unsigned short* __restrict__ qg, const unsigned short* __restrict__ kpl,
    const unsigned short* __restrict__ vtpl, const unsigned long long* __restrict__ bm,
    unsigned short* __restrict__ opart, float* __restrict__ lpart)
{
  __shared__ unsigned short Ks[128*72];   // [key][d], stride 72
  __shared__ unsigned short Vt[64*136];   // [d][key], stride 136
  int tid = threadIdx.x;
  int lane = tid & 63, w = tid >> 6;
  int l31 = lane & 31, hi5 = lane >> 5;
  int bid = blockIdx.x;
  int p = bid & 15, u = bid >> 4;
  int qtile = u >> 2, range = u & 3;
  int h = p & 7, b = p >> 3;
  const size_t sbase = (size_t)(b*H_N + h) * S_LEN;
  int kt0 = range*4, kt1 = kt0 + 3;        // 128-key tiles
  if (MODE == 0) {
    if (kt0 > qtile) return;               // inactive: consumer won't read
    if (kt1 > qtile) kt1 = qtile;
  }
  int wbase = qtile*128 + w*32;            // wave's first q-row
  int qrow = wbase + l31;
  short8 qf[4];
  #pragma unroll
  for (int km = 0; km < 4; km++)
    qf[km] = *(const short8*)&qg[(sbase + qrow)*DK_N + km*16 + hi5*8];

  int krow = tid >> 1, kc0 = (tid & 1) * 32;   // K staging: 128 rows x 64 cols
  int vd   = tid >> 2, vc0 = (tid & 3) * 32;   // V staging: 64 d-rows x 128 cols
  const unsigned short* kbase = &kpl[(sbase + krow)*DK_N + kc0];
  const unsigned short* vbase = &vtpl[((size_t)(b*H_N + h)*DK_N + vd)*S_LEN + vc0];

  f32x16 oa0 = {}, oa1 = {};
  float lp = 0.f;
  for (int kt = kt0; kt <= kt1; kt++) {
    __syncthreads();
    {
      const unsigned short* kg = kbase + (size_t)kt*128*DK_N;
      #pragma unroll
      for (int j = 0; j < 4; j++)
        *(short8*)&Ks[krow*72 + kc0 + j*8] = *(const short8*)(kg + j*8);
      const unsigned short* vg = vbase + kt*128;
      #pragma unroll
      for (int j = 0; j < 4; j++)
        *(short8*)&Vt[vd*136 + vc0 + j*8] = *(const short8*)(vg + j*8);
    }
    __syncthreads();
    #pragma unroll
    for (int kb = 0; kb < 4; kb++) {
      int kstart = kt*128 + kb*32;
      if (MODE == 0 && kstart > wbase + 31) continue;   // fully masked (wave-uniform)
      bool dmask = (MODE == 0) && (kstart + 31 > wbase);
      f32x16 sa = {};
      __builtin_amdgcn_s_setprio(1);
      #pragma unroll
      for (int km = 0; km < 4; km++) {
        short8 kf = *(const short8*)&Ks[(kb*32 + l31)*72 + km*16 + hi5*8];
        sa = __builtin_amdgcn_mfma_f32_32x32x16_bf16(kf, qf[km], sa, 0, 0, 0);
      }
      __builtin_amdgcn_s_setprio(0);
      float pv[16];
      float psum = 0.f;
      if (MODE == 1) {
        unsigned mlo = (unsigned)(bm[b*32 + kt*2 + (kb>>1)] >> ((kb&1)*32 + 4*hi5));
        #pragma unroll
        for (int r = 0; r < 16; r++) {
          const int pos = (r & 3) + 8*(r >> 2);
          float e = __expf(sa[r]);
          if ((mlo >> pos) & 1u) e = 0.f;
          pv[r] = e; psum += e;
        }
      } else if (dmask) {
        #pragma unroll
        for (int r = 0; r < 16; r++) {
          const int pos = (r & 3) + 8*(r >> 2);
          float e = __expf(sa[r]);
          if (kstart + 4*hi5 + pos > qrow) e = 0.f;
          pv[r] = e; psum += e;
        }
      } else {
        #pragma unroll
        for (int r = 0; r < 16; r++) {
          float e = __expf(sa[r]);
          pv[r] = e; psum += e;
        }
      }
      lp += psum;
      unsigned pk[8];
      #pragma unroll
      for (int i = 0; i < 8; i++)
        asm("v_cvt_pk_bf16_f32 %0, %1, %2" : "=v"(pk[i]) : "v"(pv[2*i]), "v"(pv[2*i+1]));
      asm("v_permlane32_swap_b32 %0, %1" : "+v"(pk[0]), "+v"(pk[2]));
      asm("v_permlane32_swap_b32 %0, %1" : "+v"(pk[1]), "+v"(pk[3]));
      asm("v_permlane32_swap_b32 %0, %1" : "+v"(pk[4]), "+v"(pk[6]));
      asm("v_permlane32_swap_b32 %0, %1" : "+v"(pk[5]), "+v"(pk[7]));
      uint4v f0v, f1v;
      f0v.x = pk[0]; f0v.y = pk[1]; f0v.z = pk[2]; f0v.w = pk[3];
      f1v.x = pk[4]; f1v.y = pk[5]; f1v.z = pk[6]; f1v.w = pk[7];
      short8 pf0 = *(short8*)&f0v;
      short8 pf1 = *(short8*)&f1v;
      __builtin_amdgcn_s_setprio(1);
      {
        short8 v00 = *(const short8*)&Vt[(     l31)*136 + kb*32 +      hi5*8];
        short8 v01 = *(const short8*)&Vt[(     l31)*136 + kb*32 + 16 + hi5*8];
        oa0 = __builtin_amdgcn_mfma_f32_32x32x16_bf16(pf0, v00, oa0, 0, 0, 0);
        oa0 = __builtin_amdgcn_mfma_f32_32x32x16_bf16(pf1, v01, oa0, 0, 0, 0);
        short8 v10 = *(const short8*)&Vt[(32 + l31)*136 + kb*32 +      hi5*8];
        short8 v11 = *(const short8*)&Vt[(32 + l31)*136 + kb*32 + 16 + hi5*8];
        oa1 = __builtin_amdgcn_mfma_f32_32x32x16_bf16(pf0, v10, oa1, 0, 0, 0);
        oa1 = __builtin_amdgcn_mfma_f32_32x32x16_bf16(pf1, v11, oa1, 0, 0, 0);
      }
      __builtin_amdgcn_s_setprio(0);
    }
  }
  float lptot = lp + __shfl_xor(lp, 32);
  if (lane < 32)
    lpart[((size_t)sbase + wbase + l31)*4 + range] = lptot;
  #pragma unroll
  for (int r = 0; r < 16; r++) {
    const int pos = (r & 3) + 8*(r >> 2);
    int qr = wbase + pos + 4*hi5;
    size_t obase = (size_t)range*QSZ + (sbase + (size_t)qr)*DK_N;
    opart[obase + l31]      = f2b(oa0[r]);
    opart[obase + 32 + l31] = f2b(oa1[r]);
  }
}

// ---- merge key-range partials: o = sum(O_r)/sum(l_r). CAUSAL: only (s>>9)+1 ranges. ----
template<int CAUSAL>
__global__ __launch_bounds__(256) void attn_combine4(
    const unsigned short* __restrict__ op, const float* __restrict__ lp,
    unsigned short* __restrict__ o)
{
  int t = blockIdx.x*256 + threadIdx.x;
  int f = t*8;
  int col = f & 511, row = f >> 9;
  int h = col >> 6, d = col & 63, s = row >> 1, b = row & 1;
  size_t pr = ((size_t)b*H_N + h)*S_LEN + s;
  size_t base = pr*DK_N + d;
  int nact = CAUSAL ? ((s >> 9) + 1) : 4;
  float4 lv = *(const float4*)(lp + pr*4);
  float l = lv.x;
  if (!CAUSAL || nact > 1) l += lv.y;
  if (!CAUSAL || nact > 2) l += lv.z;
  if (!CAUSAL || nact > 3) l += lv.w;
  float acc[8] = {0.f,0.f,0.f,0.f,0.f,0.f,0.f,0.f};
  #pragma unroll
  for (int r = 0; r < 4; r++) {
    if (!CAUSAL || r < nact) {
      short8 a = *(const short8*)&op[(size_t)r*QSZ + base];
      #pragma unroll
      for (int i = 0; i < 8; i++) acc[i] += b2f((unsigned short)a[i]);
    }
  }
  float inv = 1.f / l;
  short8 r8;
  #pragma unroll
  for (int i = 0; i < 8; i++) r8[i] = (short)f2b(acc[i] * inv);
  *(short8*)&o[(size_t)row*DM + col] = r8;
}

extern "C" void kernel_launch(void* const* d_in, const int* in_sizes, int n_in,
                              void* d_out, int out_size, void* d_ws, size_t ws_size,
                              hipStream_t stream) {
  const float* x       = (const float*)d_in[0];
  const float* memory  = (const float*)d_in[1];
  const int*   memmask = (const int*)d_in[3];
  const float* sa_W = (const float*)d_in[4];
  const float* sa_b = (const float*)d_in[5];
  const float* ca_W = (const float*)d_in[6];
  const float* ca_b = (const float*)d_in[7];
  const float* w1   = (const float*)d_in[8];
  const float* b1   = (const float*)d_in[9];
  const float* w2   = (const float*)d_in[10];
  const float* b2   = (const float*)d_in[11];
  const float* ln_g = (const float*)d_in[12];
  const float* ln_b = (const float*)d_in[13];
  float* out = (float*)d_out;

  char* ws = (char*)d_ws;
  float*          xcur   = (float*)ws;                              // 0..8 MB
  unsigned short* nx_bf  = (unsigned short*)(ws + (8u<<20));        // 8..12 MB
  unsigned short* qkv_sa = (unsigned short*)(ws + (12u<<20));       // 12..24 MB
  unsigned short* q_ca   = (unsigned short*)(ws + (24u<<20));       // 24..28 MB
  unsigned short* kv_ca  = (unsigned short*)(ws + (28u<<20));       // 28..36 MB
  unsigned short* o_bf   = (unsigned short*)(ws + (36u<<20));       // 36..40 MB
  unsigned short* mem_bf = (unsigned short*)(ws + (40u<<20));       // 40..44 MB
  unsigned short* h_bf   = (unsigned short*)(ws + (44u<<20));       // 44..60 MB (FFN hidden)
  unsigned short* opart  = (unsigned short*)(ws + (44u<<20));       // 44..60 MB (attn phases)
  unsigned short* fpart  = (unsigned short*)(ws + (12u<<20));       // 12..20 MB (FFN2 bf16 partials)
  float*          lpart  = (float*)(ws + (60u<<20));                // 60..60.5 MB ([pr][4])
  unsigned long long* bmsk = (unsigned long long*)(ws + (60u<<20) + (1u<<19)); // 512 B
  unsigned short* w_sa   = (unsigned short*)(ws + (61u<<20));       // weights bf16
  unsigned short* w_ca   = w_sa + 4*512*512;
  unsigned short* w_f1   = w_ca + 4*512*512;
  unsigned short* w_f2   = w_f1 + 2048*512;

  dim3 blk(256);
  dim3 g512 (512/64,  4096/64);
  dim3 gdual(20, 4096/128);
  dim3 q128_2048(2048/128, 4096/128);
  dim3 gsplitk(512/64, 4096/64, 2);

  // prep: casts + maskpack + LN1
  prep_kernel<<<7169, blk, 0, stream>>>(sa_W, ca_W, w1, w2, memory, memmask,
                                        x, ln_g, ln_b,
                                        w_sa, w_ca, w_f1, w_f2, mem_bf, bmsk, nx_bf);

  // ---- self-attention block (+ cross K/V GEMM merged) ----
  gemm128_dual<<<gdual, blk, 0, stream>>>(nx_bf, w_sa, sa_b, qkv_sa,
                                          mem_bf, w_ca + 262144, ca_b + 512, kv_ca);
  attn4<0><<<1024, blk, 0, stream>>>(qkv_sa, qkv_sa + QSZ, qkv_sa + 2*QSZ, nullptr, opart, lpart);
  attn_combine4<1><<<1024, blk, 0, stream>>>(opart, lpart, o_bf);
  gemm_bt<0,0,1><<<g512, blk, 0, stream>>>(o_bf, w_sa + 3*262144, sa_b + 1536, x, xcur, nullptr, 4096, 512, 512, 512);

  // ---- cross-attention block ----
  ln4_kernel<<<1024, blk, 0, stream>>>(xcur, ln_g + 512, ln_b + 512, nx_bf);
  gemm_bt<0,2,0><<<g512, blk, 0, stream>>>(nx_bf, w_ca, ca_b, nullptr, nullptr, q_ca, 4096, 512, 512, 512);
  attn4<1><<<1024, blk, 0, stream>>>(q_ca, kv_ca, kv_ca + QSZ, bmsk, opart, lpart);
  attn_combine4<0><<<1024, blk, 0, stream>>>(opart, lpart, o_bf);
  gemm_bt<0,0,1><<<g512, blk, 0, stream>>>(o_bf, w_ca + 3*262144, ca_b + 1536, xcur, xcur, nullptr, 4096, 512, 512, 512);

  // ---- FFN block ----
  ln4_kernel<<<1024, blk, 0, stream>>>(xcur, ln_g + 1024, ln_b + 1024, nx_bf);
  gemm128<1,1,0><<<q128_2048, blk, 0, stream>>>(nx_bf, w_f1, b1, h_bf, 4096, 2048, 512);
  gemm_bt<0,3,0><<<gsplitk, blk, 0, stream>>>(h_bf, w_f2, nullptr, nullptr, nullptr, fpart, 4096, 512, 1024, 2048);
  ffn2_combine<<<1024, blk, 0, stream>>>(fpart, b2, xcur, out);
}

// Round 14
// 184.984 us; speedup vs baseline: 1.0721x; 1.0721x over previous
//
#include <hip/hip_runtime.h>

#define S_LEN 2048
#define BATCH_N 2
#define DM 512
#define H_N 8
#define DK_N 64
#define FF_N 2048
#define M_TOK (S_LEN*BATCH_N)  // 4096
#define QSZ (BATCH_N*H_N*S_LEN*DK_N)  // 2097152 elements per q/k/v plane
#define MN_PART 2097152          // 4096*512 elems per FFN2 partial (bf16)

typedef __attribute__((ext_vector_type(8))) short short8;
typedef __attribute__((ext_vector_type(4))) float f32x4;
typedef __attribute__((ext_vector_type(16))) float f32x16;
typedef __attribute__((ext_vector_type(4))) unsigned uint4v;

__device__ __forceinline__ unsigned short f2b(float f) {
  union { float f; unsigned u; } v; v.f = f;
  unsigned r = v.u + 0x7FFFu + ((v.u >> 16) & 1u);
  return (unsigned short)(r >> 16);
}
__device__ __forceinline__ float b2f(unsigned short u) {
  union { unsigned u; float f; } v; v.u = ((unsigned)u) << 16; return v.f;
}

// async global->LDS, 16B per lane (dest = wave-uniform base + lane*16).
__device__ __forceinline__ void gl_lds16(const void* g, void* l) {
  __builtin_amdgcn_global_load_lds(
      (__attribute__((address_space(1))) unsigned int*)(unsigned long long)g,
      (__attribute__((address_space(3))) unsigned int*)(unsigned int)(unsigned long long)l,
      16, 0, 0);
}

__device__ __forceinline__ void cast4(const float* __restrict__ src,
                                      unsigned short* __restrict__ dst, int i) {
  float4 v = *(const float4*)(src + i);
  ushort4 o; o.x = f2b(v.x); o.y = f2b(v.y); o.z = f2b(v.z); o.w = f2b(v.w);
  *(ushort4*)(dst + i) = o;
}

// ---- wave-per-row LayerNorm (512 cols, 8 f32/lane, shfl-only) ----
__device__ __forceinline__ void ln_row_wave(const float* __restrict__ in,
    const float* __restrict__ g, const float* __restrict__ b,
    unsigned short* __restrict__ out, int row, int lane) {
  const float4* src = (const float4*)(in + (size_t)row * DM);
  float4 v0 = src[lane*2], v1 = src[lane*2 + 1];
  float s  = v0.x+v0.y+v0.z+v0.w + v1.x+v1.y+v1.z+v1.w;
  float ss = v0.x*v0.x+v0.y*v0.y+v0.z*v0.z+v0.w*v0.w
           + v1.x*v1.x+v1.y*v1.y+v1.z*v1.z+v1.w*v1.w;
  #pragma unroll
  for (int off = 32; off >= 1; off >>= 1) {
    s  += __shfl_xor(s,  off);
    ss += __shfl_xor(ss, off);
  }
  float mean = s * (1.f/512.f);
  float inv  = rsqrtf(ss * (1.f/512.f) - mean*mean + 1e-5f);
  float4 g0 = ((const float4*)g)[lane*2], g1 = ((const float4*)g)[lane*2 + 1];
  float4 b0 = ((const float4*)b)[lane*2], b1 = ((const float4*)b)[lane*2 + 1];
  ushort4 o0, o1;
  o0.x = f2b((v0.x-mean)*inv*g0.x + b0.x);
  o0.y = f2b((v0.y-mean)*inv*g0.y + b0.y);
  o0.z = f2b((v0.z-mean)*inv*g0.z + b0.z);
  o0.w = f2b((v0.w-mean)*inv*g0.w + b0.w);
  o1.x = f2b((v1.x-mean)*inv*g1.x + b1.x);
  o1.y = f2b((v1.y-mean)*inv*g1.y + b1.y);
  o1.z = f2b((v1.z-mean)*inv*g1.z + b1.z);
  o1.w = f2b((v1.w-mean)*inv*g1.w + b1.w);
  ushort4* dst = (ushort4*)(out + (size_t)row * DM);
  dst[lane*2]     = o0;
  dst[lane*2 + 1] = o1;
}

// ---- fused prep: weight/memory casts + mask pack + LN1 ----
__global__ __launch_bounds__(256) void prep_kernel(
    const float* __restrict__ sa_W, const float* __restrict__ ca_W,
    const float* __restrict__ w1, const float* __restrict__ w2,
    const float* __restrict__ memory, const int* __restrict__ mm,
    const float* __restrict__ x, const float* __restrict__ ln_g,
    const float* __restrict__ ln_b,
    unsigned short* __restrict__ o_sa, unsigned short* __restrict__ o_ca,
    unsigned short* __restrict__ o_w1, unsigned short* __restrict__ o_w2,
    unsigned short* __restrict__ o_mem, unsigned long long* __restrict__ bmo,
    unsigned short* __restrict__ nx)
{
  int blk = blockIdx.x, t = threadIdx.x;
  if (blk < 1024)      cast4(sa_W, o_sa, (blk*256 + t)*4);
  else if (blk < 2048) cast4(ca_W, o_ca, ((blk-1024)*256 + t)*4);
  else if (blk < 3072) cast4(w1,   o_w1, ((blk-2048)*256 + t)*4);
  else if (blk < 4096) cast4(w2,   o_w2, ((blk-3072)*256 + t)*4);
  else if (blk < 6144) cast4(memory, o_mem, ((blk-4096)*256 + t)*4);
  else if (blk == 6144) {
    if (t < 64) {
      int b = t >> 5, kt = t & 31;
      unsigned long long m = 0ull;
      for (int j = 0; j < 64; j++)
        m |= (unsigned long long)(mm[b*S_LEN + kt*64 + j] != 0) << j;
      bmo[b*32 + kt] = m;
    }
  } else {
    int row = (blk - 6145)*4 + (t >> 6);
    ln_row_wave(x, ln_g, ln_b, nx, row, t & 63);
  }
}

// ---- standalone LN (4 rows / 256-thr block) ----
__global__ __launch_bounds__(256) void ln4_kernel(const float* __restrict__ in,
                                                  const float* __restrict__ g,
                                                  const float* __restrict__ b,
                                                  unsigned short* __restrict__ out) {
  ln_row_wave(in, g, b, out, blockIdx.x*4 + (threadIdx.x >> 6), threadIdx.x & 63);
}

// ---- 64x64-tile GEMM, dbuf single-barrier.
// OUTMODE 0: f32 +resid, 1: bf16, 2: bf16 qkv scatter (Q plane pre-scaled 1/8),
// 3: bf16 split-K partial (no bias).
template<int RELU, int OUTMODE, int RESID>
__global__ __launch_bounds__(256) void gemm_bt(
    const unsigned short* __restrict__ A, const unsigned short* __restrict__ W,
    const float* __restrict__ bias, const float* __restrict__ resid,
    float* __restrict__ Cf, unsigned short* __restrict__ Cb,
    int M, int N, int K, int Kstride)
{
  __shared__ unsigned short As[2][64*40];
  __shared__ unsigned short Bs[2][64*40];
  int tid = threadIdx.x;
  int lane = tid & 63, w = tid >> 6;
  int wr = w >> 1, wc = w & 1;
  int bm = blockIdx.y * 64, bn = blockIdx.x * 64;
  int kz = blockIdx.z;
  f32x4 acc[2][2] = {};
  int lrow = tid >> 2;
  int lcg  = (tid & 3) * 8;
  const size_t aoff = (size_t)(bm + lrow) * Kstride + (size_t)kz * K + lcg;
  const size_t boff = (size_t)(bn + lrow) * Kstride + (size_t)kz * K + lcg;
  int fr = lane & 15, kg = (lane >> 4) * 8;
  short8 pa = *(const short8*)&A[aoff];
  short8 pb = *(const short8*)&W[boff];
  *(short8*)&As[0][lrow*40 + lcg] = pa;
  *(short8*)&Bs[0][lrow*40 + lcg] = pb;
  __syncthreads();
  int cur = 0;
  for (int k0 = 0; k0 < K; k0 += 32) {
    bool hn = (k0 + 32) < K;
    if (hn) {
      pa = *(const short8*)&A[aoff + k0 + 32];
      pb = *(const short8*)&W[boff + k0 + 32];
    }
    short8 af0 = *(const short8*)&As[cur][(wr*32 +      fr)*40 + kg];
    short8 af1 = *(const short8*)&As[cur][(wr*32 + 16 + fr)*40 + kg];
    short8 bf0 = *(const short8*)&Bs[cur][(wc*32 +      fr)*40 + kg];
    short8 bf1 = *(const short8*)&Bs[cur][(wc*32 + 16 + fr)*40 + kg];
    acc[0][0] = __builtin_amdgcn_mfma_f32_16x16x32_bf16(af0, bf0, acc[0][0], 0,0,0);
    acc[0][1] = __builtin_amdgcn_mfma_f32_16x16x32_bf16(af0, bf1, acc[0][1], 0,0,0);
    acc[1][0] = __builtin_amdgcn_mfma_f32_16x16x32_bf16(af1, bf0, acc[1][0], 0,0,0);
    acc[1][1] = __builtin_amdgcn_mfma_f32_16x16x32_bf16(af1, bf1, acc[1][1], 0,0,0);
    if (hn) {
      *(short8*)&As[cur^1][lrow*40 + lcg] = pa;
      *(short8*)&Bs[cur^1][lrow*40 + lcg] = pb;
    }
    __syncthreads();
    cur ^= 1;
  }
  int rbase = (lane >> 4) * 4;
  #pragma unroll
  for (int m = 0; m < 2; m++) {
    #pragma unroll
    for (int n = 0; n < 2; n++) {
      int col = bn + wc*32 + n*16 + (lane & 15);
      float bc = (OUTMODE == 3) ? 0.f : bias[col];
      #pragma unroll
      for (int r = 0; r < 4; r++) {
        int row = bm + wr*32 + m*16 + rbase + r;
        float vv = acc[m][n][r] + bc;
        if (RELU) vv = fmaxf(vv, 0.f);
        if (OUTMODE == 2) {
          int which = col >> 9, hh = (col >> 6) & 7, dd = col & 63;
          if (which == 0) vv *= 0.125f;   // fold 1/sqrt(dk) into Q plane
          size_t idx = ((((size_t)which*BATCH_N + (row & 1))*H_N + hh)*S_LEN + (row >> 1))*DK_N + dd;
          Cb[idx] = f2b(vv);
        } else if (OUTMODE == 3) {
          Cb[(size_t)kz*MN_PART + (size_t)row*N + col] = f2b(vv);
        } else {
          size_t idx = (size_t)row * N + col;
          if (RESID) vv += resid[idx];
          if (OUTMODE == 1) Cb[idx] = f2b(vv);
          else              Cf[idx] = vv;
        }
      }
    }
  }
}

// ---- FFN2 split-K(2) combine: out = p0 + p1 + bias + resid (partials bf16) ----
__global__ __launch_bounds__(256) void ffn2_combine(
    const unsigned short* __restrict__ part, const float* __restrict__ bias,
    const float* __restrict__ resid, float* __restrict__ out)
{
  int i = (blockIdx.x*256 + threadIdx.x)*8;
  short8 a = *(const short8*)&part[i];
  short8 b = *(const short8*)&part[MN_PART + i];
  float4 bs0 = *(const float4*)(bias + (i & 511));
  float4 bs1 = *(const float4*)(bias + ((i & 511) + 4));
  float4 rs0 = *(const float4*)(resid + i);
  float4 rs1 = *(const float4*)(resid + i + 4);
  float4 o0, o1;
  o0.x = b2f((unsigned short)a[0]) + b2f((unsigned short)b[0]) + bs0.x + rs0.x;
  o0.y = b2f((unsigned short)a[1]) + b2f((unsigned short)b[1]) + bs0.y + rs0.y;
  o0.z = b2f((unsigned short)a[2]) + b2f((unsigned short)b[2]) + bs0.z + rs0.z;
  o0.w = b2f((unsigned short)a[3]) + b2f((unsigned short)b[3]) + bs0.w + rs0.w;
  o1.x = b2f((unsigned short)a[4]) + b2f((unsigned short)b[4]) + bs1.x + rs1.x;
  o1.y = b2f((unsigned short)a[5]) + b2f((unsigned short)b[5]) + bs1.y + rs1.y;
  o1.z = b2f((unsigned short)a[6]) + b2f((unsigned short)b[6]) + bs1.z + rs1.z;
  o1.w = b2f((unsigned short)a[7]) + b2f((unsigned short)b[7]) + bs1.w + rs1.w;
  *(float4*)(out + i)     = o0;
  *(float4*)(out + i + 4) = o1;
}

// ---- 128x128-tile GEMM, global_load_lds staging (FFN1) ----
template<int RELU, int OUTMODE, int VSTART>
__global__ __launch_bounds__(256) void gemm128(
    const unsigned short* __restrict__ A, const unsigned short* __restrict__ W,
    const float* __restrict__ bias, unsigned short* __restrict__ Cb,
    int M, int N, int K)
{
  __shared__ unsigned short As[128*32];
  __shared__ unsigned short Bs[128*32];
  int tid = threadIdx.x, lane = tid & 63, w = tid >> 6;
  int bm = blockIdx.y * 128, bn = blockIdx.x * 128;
  int fr = lane & 15, hi = lane >> 4;
  int kg8 = hi*8, rg = hi*4;
  int wm = (w >> 1) * 64, wn = (w & 1) * 64;
  f32x4 acc[4][4] = {};
  const unsigned short* ga0 = A + (size_t)(bm +      (tid>>2))*K + (tid&3)*8;
  const unsigned short* ga1 = A + (size_t)(bm + 64 + (tid>>2))*K + (tid&3)*8;
  const unsigned short* gb0 = W + (size_t)(bn +      (tid>>2))*K + (tid&3)*8;
  const unsigned short* gb1 = W + (size_t)(bn + 64 + (tid>>2))*K + (tid&3)*8;
  unsigned short* lA0 = &As[tid*8];
  unsigned short* lA1 = &As[2048 + tid*8];
  unsigned short* lB0 = &Bs[tid*8];
  unsigned short* lB1 = &Bs[2048 + tid*8];
  for (int k0 = 0; k0 < K; k0 += 32) {
    gl_lds16(ga0 + k0, lA0);
    gl_lds16(ga1 + k0, lA1);
    gl_lds16(gb0 + k0, lB0);
    gl_lds16(gb1 + k0, lB1);
    __syncthreads();
    short8 af[4], bf[4];
    #pragma unroll
    for (int m = 0; m < 4; m++) af[m] = *(const short8*)&As[(wm + m*16 + fr)*32 + kg8];
    #pragma unroll
    for (int n = 0; n < 4; n++) bf[n] = *(const short8*)&Bs[(wn + n*16 + fr)*32 + kg8];
    __builtin_amdgcn_s_setprio(1);
    #pragma unroll
    for (int m = 0; m < 4; m++)
      #pragma unroll
      for (int n = 0; n < 4; n++)
        acc[m][n] = __builtin_amdgcn_mfma_f32_16x16x32_bf16(af[m], bf[n], acc[m][n], 0,0,0);
    __builtin_amdgcn_s_setprio(0);
    __syncthreads();
  }
  #pragma unroll
  for (int m = 0; m < 4; m++) {
    #pragma unroll
    for (int n = 0; n < 4; n++) {
      int col = bn + wn + n*16 + fr;
      float bc = bias[col];
      #pragma unroll
      for (int r = 0; r < 4; r++) {
        int row = bm + wm + m*16 + rg + r;
        float vv = acc[m][n][r] + bc;
        if (RELU) vv = fmaxf(vv, 0.f);
        if (OUTMODE == 2) {
          int which = col >> 9, hh = (col >> 6) & 7, dd = col & 63;
          int srow = row >> 1, bb = row & 1;
          size_t idx;
          if (which >= VSTART)
            idx = (size_t)which*QSZ + (((size_t)bb*H_N + hh)*DK_N + dd)*S_LEN + srow;
          else
            idx = (size_t)which*QSZ + (((size_t)bb*H_N + hh)*S_LEN + srow)*DK_N + dd;
          Cb[idx] = f2b(vv);
        } else {
          Cb[(size_t)row * N + col] = f2b(vv);
        }
      }
    }
  }
}

// ---- merged self-QKV (12 col-tiles) + cross-KV (8 col-tiles) GEMM ----
// Self Q plane (vs==2, which==0) is pre-scaled by 1/8 (1/sqrt(dk)).
__global__ __launch_bounds__(256) void gemm128_dual(
    const unsigned short* __restrict__ A0, const unsigned short* __restrict__ W0,
    const float* __restrict__ bias0, unsigned short* __restrict__ C0,
    const unsigned short* __restrict__ A1, const unsigned short* __restrict__ W1,
    const float* __restrict__ bias1, unsigned short* __restrict__ C1)
{
  const int K = 512;
  int bx = blockIdx.x;
  const unsigned short* A; const unsigned short* W; const float* bias;
  unsigned short* Cb; int bn, vs;
  if (bx < 12) { A = A0; W = W0; bias = bias0; Cb = C0; bn = bx*128;      vs = 2; }
  else         { A = A1; W = W1; bias = bias1; Cb = C1; bn = (bx-12)*128; vs = 1; }
  __shared__ unsigned short As[128*32];
  __shared__ unsigned short Bs[128*32];
  int tid = threadIdx.x, lane = tid & 63, w = tid >> 6;
  int bm = blockIdx.y * 128;
  int fr = lane & 15, hi = lane >> 4;
  int kg8 = hi*8, rg = hi*4;
  int wm = (w >> 1) * 64, wn = (w & 1) * 64;
  f32x4 acc[4][4] = {};
  const unsigned short* ga0 = A + (size_t)(bm +      (tid>>2))*K + (tid&3)*8;
  const unsigned short* ga1 = A + (size_t)(bm + 64 + (tid>>2))*K + (tid&3)*8;
  const unsigned short* gb0 = W + (size_t)(bn +      (tid>>2))*K + (tid&3)*8;
  const unsigned short* gb1 = W + (size_t)(bn + 64 + (tid>>2))*K + (tid&3)*8;
  unsigned short* lA0 = &As[tid*8];
  unsigned short* lA1 = &As[2048 + tid*8];
  unsigned short* lB0 = &Bs[tid*8];
  unsigned short* lB1 = &Bs[2048 + tid*8];
  for (int k0 = 0; k0 < K; k0 += 32) {
    gl_lds16(ga0 + k0, lA0);
    gl_lds16(ga1 + k0, lA1);
    gl_lds16(gb0 + k0, lB0);
    gl_lds16(gb1 + k0, lB1);
    __syncthreads();
    short8 af[4], bf[4];
    #pragma unroll
    for (int m = 0; m < 4; m++) af[m] = *(const short8*)&As[(wm + m*16 + fr)*32 + kg8];
    #pragma unroll
    for (int n = 0; n < 4; n++) bf[n] = *(const short8*)&Bs[(wn + n*16 + fr)*32 + kg8];
    __builtin_amdgcn_s_setprio(1);
    #pragma unroll
    for (int m = 0; m < 4; m++)
      #pragma unroll
      for (int n = 0; n < 4; n++)
        acc[m][n] = __builtin_amdgcn_mfma_f32_16x16x32_bf16(af[m], bf[n], acc[m][n], 0,0,0);
    __builtin_amdgcn_s_setprio(0);
    __syncthreads();
  }
  #pragma unroll
  for (int m = 0; m < 4; m++) {
    #pragma unroll
    for (int n = 0; n < 4; n++) {
      int col = bn + wn + n*16 + fr;
      float bc = bias[col];
      #pragma unroll
      for (int r = 0; r < 4; r++) {
        int row = bm + wm + m*16 + rg + r;
        float vv = acc[m][n][r] + bc;
        int which = col >> 9, hh = (col >> 6) & 7, dd = col & 63;
        if (vs == 2 && which == 0) vv *= 0.125f;   // Q plane pre-scale
        int srow = row >> 1, bb = row & 1;
        size_t idx;
        if (which >= vs)
          idx = (size_t)which*QSZ + (((size_t)bb*H_N + hh)*DK_N + dd)*S_LEN + srow;
        else
          idx = (size_t)which*QSZ + (((size_t)bb*H_N + hh)*S_LEN + srow)*DK_N + dd;
        Cb[idx] = f2b(vv);
      }
    }
  }
}

// ---- 32x32-MFMA flash attention: 128 q-rows/block, wave owns full rows ----
// Q pre-scaled by 1/sqrt(dk). Causal mask only on each wave's diagonal tile
// (wave-uniform); tiles past the wave's rows skipped; inactive causal blocks
// return WITHOUT writing (combine reads only active ranges).
// lpart layout: [pr][4].
template<int MODE>
__global__ __launch_bounds__(256, 4) void attn3(
    const unsigned short* __restrict__ qg, const unsigned short* __restrict__ kpl,
    const unsigned short* __restrict__ vtpl, const unsigned long long* __restrict__ bm,
    unsigned short* __restrict__ opart, float* __restrict__ lpart)
{
  __shared__ unsigned short SM[2*64*72];   // Ks | Vt
  unsigned short* Ks = SM;
  unsigned short* Vt = SM + 64*72;
  int tid = threadIdx.x;
  int lane = tid & 63, w = tid >> 6;
  int l31 = lane & 31, hi5 = lane >> 5;
  int bid = blockIdx.x;
  int p = bid & 15, u = bid >> 4;
  int qtile = u >> 2, range = u & 3;
  int h = p & 7, b = p >> 3;
  const size_t sbase = (size_t)(b*H_N + h) * S_LEN;
  int kt0 = range*8, kt1 = kt0 + 7;
  if (MODE == 0) {
    if (kt0 > qtile*2 + 1) return;           // inactive: consumer won't read
    if (kt1 > qtile*2 + 1) kt1 = qtile*2 + 1;
  }
  int wbase = qtile*128 + w*32;              // wave's first q-row
  int ktw = (wbase + 31) >> 6;               // wave's diagonal key-tile (MODE 0)
  int qrow = wbase + l31;
  short8 qf[4];
  #pragma unroll
  for (int km = 0; km < 4; km++)
    qf[km] = *(const short8*)&qg[(sbase + qrow)*DK_N + km*16 + hi5*8];

  int sr = tid >> 2, sc = (tid & 3) * 16;
  const unsigned short* kbase = &kpl[(sbase + sr)*DK_N + sc];
  const unsigned short* vbase = &vtpl[((size_t)(b*H_N + h)*DK_N + sr)*S_LEN + sc];

  f32x16 oa0 = {}, oa1 = {};
  float lp = 0.f;
  for (int kt = kt0; kt <= kt1; kt++) {
    __syncthreads();
    {
      const unsigned short* kg = kbase + (size_t)kt*64*DK_N;
      const unsigned short* vg = vbase + kt*64;
      *(short8*)&Ks[sr*72 + sc]     = *(const short8*)kg;
      *(short8*)&Ks[sr*72 + sc + 8] = *(const short8*)(kg + 8);
      *(short8*)&Vt[sr*72 + sc]     = *(const short8*)vg;
      *(short8*)&Vt[sr*72 + sc + 8] = *(const short8*)(vg + 8);
    }
    __syncthreads();
    if (MODE == 0 && kt > ktw) continue;     // wave-uniform; barriers balanced
    bool dmask = (MODE == 0) && (kt == ktw);
    #pragma unroll
    for (int kb = 0; kb < 2; kb++) {
      f32x16 sa = {};
      __builtin_amdgcn_s_setprio(1);
      #pragma unroll
      for (int km = 0; km < 4; km++) {
        short8 kf = *(const short8*)&Ks[(kb*32 + l31)*72 + km*16 + hi5*8];
        sa = __builtin_amdgcn_mfma_f32_32x32x16_bf16(kf, qf[km], sa, 0, 0, 0);
      }
      __builtin_amdgcn_s_setprio(0);
      float pv[16];
      float psum = 0.f;
      if (MODE == 1) {
        unsigned mlo = (unsigned)(bm[b*32 + kt] >> (kb*32 + 4*hi5));
        #pragma unroll
        for (int r = 0; r < 16; r++) {
          const int pos = (r & 3) + 8*(r >> 2);
          float e = __expf(sa[r]);
          if ((mlo >> pos) & 1u) e = 0.f;
          pv[r] = e; psum += e;
        }
      } else if (dmask) {
        #pragma unroll
        for (int r = 0; r < 16; r++) {
          const int pos = (r & 3) + 8*(r >> 2);
          float e = __expf(sa[r]);
          if (kt*64 + kb*32 + 4*hi5 + pos > qrow) e = 0.f;
          pv[r] = e; psum += e;
        }
      } else {
        #pragma unroll
        for (int r = 0; r < 16; r++) {
          float e = __expf(sa[r]);
          pv[r] = e; psum += e;
        }
      }
      lp += psum;
      unsigned pk[8];
      #pragma unroll
      for (int i = 0; i < 8; i++)
        asm("v_cvt_pk_bf16_f32 %0, %1, %2" : "=v"(pk[i]) : "v"(pv[2*i]), "v"(pv[2*i+1]));
      asm("v_permlane32_swap_b32 %0, %1" : "+v"(pk[0]), "+v"(pk[2]));
      asm("v_permlane32_swap_b32 %0, %1" : "+v"(pk[1]), "+v"(pk[3]));
      asm("v_permlane32_swap_b32 %0, %1" : "+v"(pk[4]), "+v"(pk[6]));
      asm("v_permlane32_swap_b32 %0, %1" : "+v"(pk[5]), "+v"(pk[7]));
      uint4v f0v, f1v;
      f0v.x = pk[0]; f0v.y = pk[1]; f0v.z = pk[2]; f0v.w = pk[3];
      f1v.x = pk[4]; f1v.y = pk[5]; f1v.z = pk[6]; f1v.w = pk[7];
      short8 pf0 = *(short8*)&f0v;
      short8 pf1 = *(short8*)&f1v;
      __builtin_amdgcn_s_setprio(1);
      {
        short8 v00 = *(const short8*)&Vt[(     l31)*72 + kb*32 +      hi5*8];
        short8 v01 = *(const short8*)&Vt[(     l31)*72 + kb*32 + 16 + hi5*8];
        oa0 = __builtin_amdgcn_mfma_f32_32x32x16_bf16(pf0, v00, oa0, 0, 0, 0);
        oa0 = __builtin_amdgcn_mfma_f32_32x32x16_bf16(pf1, v01, oa0, 0, 0, 0);
        short8 v10 = *(const short8*)&Vt[(32 + l31)*72 + kb*32 +      hi5*8];
        short8 v11 = *(const short8*)&Vt[(32 + l31)*72 + kb*32 + 16 + hi5*8];
        oa1 = __builtin_amdgcn_mfma_f32_32x32x16_bf16(pf0, v10, oa1, 0, 0, 0);
        oa1 = __builtin_amdgcn_mfma_f32_32x32x16_bf16(pf1, v11, oa1, 0, 0, 0);
      }
      __builtin_amdgcn_s_setprio(0);
    }
  }
  float lptot = lp + __shfl_xor(lp, 32);
  if (lane < 32)
    lpart[((size_t)sbase + wbase + l31)*4 + range] = lptot;
  #pragma unroll
  for (int r = 0; r < 16; r++) {
    const int pos = (r & 3) + 8*(r >> 2);
    int qr = wbase + pos + 4*hi5;
    size_t obase = (size_t)range*QSZ + (sbase + (size_t)qr)*DK_N;
    opart[obase + l31]      = f2b(oa0[r]);
    opart[obase + 32 + l31] = f2b(oa1[r]);
  }
}

// ---- merge key-range partials: o = sum(O_r)/sum(l_r). CAUSAL: only (s>>9)+1 ranges. ----
template<int CAUSAL>
__global__ __launch_bounds__(256) void attn_combine4(
    const unsigned short* __restrict__ op, const float* __restrict__ lp,
    unsigned short* __restrict__ o)
{
  int t = blockIdx.x*256 + threadIdx.x;
  int f = t*8;
  int col = f & 511, row = f >> 9;
  int h = col >> 6, d = col & 63, s = row >> 1, b = row & 1;
  size_t pr = ((size_t)b*H_N + h)*S_LEN + s;
  size_t base = pr*DK_N + d;
  int nact = CAUSAL ? ((s >> 9) + 1) : 4;
  float4 lv = *(const float4*)(lp + pr*4);
  float l = lv.x;
  if (!CAUSAL || nact > 1) l += lv.y;
  if (!CAUSAL || nact > 2) l += lv.z;
  if (!CAUSAL || nact > 3) l += lv.w;
  float acc[8] = {0.f,0.f,0.f,0.f,0.f,0.f,0.f,0.f};
  #pragma unroll
  for (int r = 0; r < 4; r++) {
    if (!CAUSAL || r < nact) {
      short8 a = *(const short8*)&op[(size_t)r*QSZ + base];
      #pragma unroll
      for (int i = 0; i < 8; i++) acc[i] += b2f((unsigned short)a[i]);
    }
  }
  float inv = 1.f / l;
  short8 r8;
  #pragma unroll
  for (int i = 0; i < 8; i++) r8[i] = (short)f2b(acc[i] * inv);
  *(short8*)&o[(size_t)row*DM + col] = r8;
}

extern "C" void kernel_launch(void* const* d_in, const int* in_sizes, int n_in,
                              void* d_out, int out_size, void* d_ws, size_t ws_size,
                              hipStream_t stream) {
  const float* x       = (const float*)d_in[0];
  const float* memory  = (const float*)d_in[1];
  const int*   memmask = (const int*)d_in[3];
  const float* sa_W = (const float*)d_in[4];
  const float* sa_b = (const float*)d_in[5];
  const float* ca_W = (const float*)d_in[6];
  const float* ca_b = (const float*)d_in[7];
  const float* w1   = (const float*)d_in[8];
  const float* b1   = (const float*)d_in[9];
  const float* w2   = (const float*)d_in[10];
  const float* b2   = (const float*)d_in[11];
  const float* ln_g = (const float*)d_in[12];
  const float* ln_b = (const float*)d_in[13];
  float* out = (float*)d_out;

  char* ws = (char*)d_ws;
  float*          xcur   = (float*)ws;                              // 0..8 MB
  unsigned short* nx_bf  = (unsigned short*)(ws + (8u<<20));        // 8..12 MB
  unsigned short* qkv_sa = (unsigned short*)(ws + (12u<<20));       // 12..24 MB
  unsigned short* q_ca   = (unsigned short*)(ws + (24u<<20));       // 24..28 MB
  unsigned short* kv_ca  = (unsigned short*)(ws + (28u<<20));       // 28..36 MB
  unsigned short* o_bf   = (unsigned short*)(ws + (36u<<20));       // 36..40 MB
  unsigned short* mem_bf = (unsigned short*)(ws + (40u<<20));       // 40..44 MB
  unsigned short* h_bf   = (unsigned short*)(ws + (44u<<20));       // 44..60 MB (FFN hidden)
  unsigned short* opart  = (unsigned short*)(ws + (44u<<20));       // 44..60 MB (attn phases)
  unsigned short* fpart  = (unsigned short*)(ws + (12u<<20));       // 12..20 MB (FFN2 bf16 partials)
  float*          lpart  = (float*)(ws + (60u<<20));                // 60..60.5 MB ([pr][4])
  unsigned long long* bmsk = (unsigned long long*)(ws + (60u<<20) + (1u<<19)); // 512 B
  unsigned short* w_sa   = (unsigned short*)(ws + (61u<<20));       // weights bf16
  unsigned short* w_ca   = w_sa + 4*512*512;
  unsigned short* w_f1   = w_ca + 4*512*512;
  unsigned short* w_f2   = w_f1 + 2048*512;

  dim3 blk(256);
  dim3 g512 (512/64,  4096/64);
  dim3 gdual(20, 4096/128);
  dim3 q128_2048(2048/128, 4096/128);
  dim3 gsplitk(512/64, 4096/64, 2);

  // prep: casts + maskpack + LN1
  prep_kernel<<<7169, blk, 0, stream>>>(sa_W, ca_W, w1, w2, memory, memmask,
                                        x, ln_g, ln_b,
                                        w_sa, w_ca, w_f1, w_f2, mem_bf, bmsk, nx_bf);

  // ---- self-attention block (+ cross K/V GEMM merged) ----
  gemm128_dual<<<gdual, blk, 0, stream>>>(nx_bf, w_sa, sa_b, qkv_sa,
                                          mem_bf, w_ca + 262144, ca_b + 512, kv_ca);
  attn3<0><<<1024, blk, 0, stream>>>(qkv_sa, qkv_sa + QSZ, qkv_sa + 2*QSZ, nullptr, opart, lpart);
  attn_combine4<1><<<1024, blk, 0, stream>>>(opart, lpart, o_bf);
  gemm_bt<0,0,1><<<g512, blk, 0, stream>>>(o_bf, w_sa + 3*262144, sa_b + 1536, x, xcur, nullptr, 4096, 512, 512, 512);

  // ---- cross-attention block ----
  ln4_kernel<<<1024, blk, 0, stream>>>(xcur, ln_g + 512, ln_b + 512, nx_bf);
  gemm_bt<0,2,0><<<g512, blk, 0, stream>>>(nx_bf, w_ca, ca_b, nullptr, nullptr, q_ca, 4096, 512, 512, 512);
  attn3<1><<<1024, blk, 0, stream>>>(q_ca, kv_ca, kv_ca + QSZ, bmsk, opart, lpart);
  attn_combine4<0><<<1024, blk, 0, stream>>>(opart, lpart, o_bf);
  gemm_bt<0,0,1><<<g512, blk, 0, stream>>>(o_bf, w_ca + 3*262144, ca_b + 1536, xcur, xcur, nullptr, 4096, 512, 512, 512);

  // ---- FFN block ----
  ln4_kernel<<<1024, blk, 0, stream>>>(xcur, ln_g + 1024, ln_b + 1024, nx_bf);
  gemm128<1,1,0><<<q128_2048, blk, 0, stream>>>(nx_bf, w_f1, b1, h_bf, 4096, 2048, 512);
  gemm_bt<0,3,0><<<gsplitk, blk, 0, stream>>>(h_bf, w_f2, nullptr, nullptr, nullptr, fpart, 4096, 512, 1024, 2048);
  ffn2_combine<<<1024, blk, 0, stream>>>(fpart, b2, xcur, out);
}